// Round 1
// baseline (91.883 us; speedup 1.0000x reference)
//
#include <hip/hip_runtime.h>

// Butterfly: out = butterfly_mult_untied(twiddle, x) + bias
// x: (32768, 1024) f32; twiddle: (1, 10, 512, 2, 2) f32; bias: (1024,) f32
// Stage idx: element n pairs with n ^ (1<<idx); matrix index p = n with bit idx removed.
// out(n) = t[idx][p][i][i]*v(n) + t[idx][p][i][1-i]*v(n^stride), i = bit idx of n.

#define ROWS_PER_BLOCK 16
#define NSTAGE 10

__global__ __launch_bounds__(256, 4)
void butterfly_kernel(const float* __restrict__ x,
                      const float* __restrict__ tw,
                      const float* __restrict__ bias,
                      float* __restrict__ out) {
    __shared__ float4 lds[2][256];
    const int tid = threadIdx.x;
    const int n0 = tid * 4;

    // Per-thread register-resident twiddle, pre-swapped to (self, partner) coeffs.
    // twm[idx][e] multiplies my own value; two_[idx][e] multiplies the partner value.
    float twm[NSTAGE][4], two_[NSTAGE][4];
#pragma unroll
    for (int idx = 0; idx < NSTAGE; ++idx) {
        const int stride = 1 << idx;
#pragma unroll
        for (int e = 0; e < 4; ++e) {
            const int n = n0 + e;
            const int p = ((n >> (idx + 1)) << idx) | (n & (stride - 1));
            const int i = (n >> idx) & 1;
            const float* tp = tw + idx * 2048 + p * 4 + i * 2;  // &t[idx][p][i][0]
            twm[idx][e]  = tp[i];       // coeff of j == i  (my own value)
            two_[idx][e] = tp[1 - i];   // coeff of j == 1-i (partner value)
        }
    }
    const float4 b4 = *reinterpret_cast<const float4*>(bias + n0);

    const long long rowbase = (long long)blockIdx.x * ROWS_PER_BLOCK;
    for (int r = 0; r < ROWS_PER_BLOCK; ++r) {
        const long long row = rowbase + r;
        const float4 v4 = *reinterpret_cast<const float4*>(x + row * 1024 + n0);
        float v[4] = {v4.x, v4.y, v4.z, v4.w};

        // stage 0 (stride 1): pairs (e0,e1),(e2,e3) — intra-thread
        {
            float a0 = twm[0][0] * v[0] + two_[0][0] * v[1];
            float a1 = twm[0][1] * v[1] + two_[0][1] * v[0];
            float a2 = twm[0][2] * v[2] + two_[0][2] * v[3];
            float a3 = twm[0][3] * v[3] + two_[0][3] * v[2];
            v[0] = a0; v[1] = a1; v[2] = a2; v[3] = a3;
        }
        // stage 1 (stride 2): pairs (e0,e2),(e1,e3) — intra-thread
        {
            float a0 = twm[1][0] * v[0] + two_[1][0] * v[2];
            float a1 = twm[1][1] * v[1] + two_[1][1] * v[3];
            float a2 = twm[1][2] * v[2] + two_[1][2] * v[0];
            float a3 = twm[1][3] * v[3] + two_[1][3] * v[1];
            v[0] = a0; v[1] = a1; v[2] = a2; v[3] = a3;
        }
        // stages 2..7 (stride 4..128): cross-lane, lane bit = idx-2
#pragma unroll
        for (int idx = 2; idx < 8; ++idx) {
            const int m = 1 << (idx - 2);
#pragma unroll
            for (int e = 0; e < 4; ++e) {
                const float o = __shfl_xor(v[e], m, 64);
                v[e] = twm[idx][e] * v[e] + two_[idx][e] * o;
            }
        }
        // stage 8 (stride 256): cross-wave, partner thread tid ^ 64
        lds[0][tid] = make_float4(v[0], v[1], v[2], v[3]);
        __syncthreads();
        {
            const float4 o4 = lds[0][tid ^ 64];
            const float o[4] = {o4.x, o4.y, o4.z, o4.w};
#pragma unroll
            for (int e = 0; e < 4; ++e)
                v[e] = twm[8][e] * v[e] + two_[8][e] * o[e];
        }
        // stage 9 (stride 512): cross-wave, partner thread tid ^ 128
        lds[1][tid] = make_float4(v[0], v[1], v[2], v[3]);
        __syncthreads();
        {
            const float4 o4 = lds[1][tid ^ 128];
            const float o[4] = {o4.x, o4.y, o4.z, o4.w};
#pragma unroll
            for (int e = 0; e < 4; ++e)
                v[e] = twm[9][e] * v[e] + two_[9][e] * o[e];
        }
        // bias + coalesced store. (Next row's lds[0] write is safe: every wave's
        // lds[0] read happened before its lds[1] write, which precedes the barrier.)
        float4 s4;
        s4.x = v[0] + b4.x; s4.y = v[1] + b4.y; s4.z = v[2] + b4.z; s4.w = v[3] + b4.w;
        *reinterpret_cast<float4*>(out + row * 1024 + n0) = s4;
    }
}

extern "C" void kernel_launch(void* const* d_in, const int* in_sizes, int n_in,
                              void* d_out, int out_size, void* d_ws, size_t ws_size,
                              hipStream_t stream) {
    const float* x    = (const float*)d_in[0];
    const float* tw   = (const float*)d_in[1];
    const float* bias = (const float*)d_in[2];
    float* outp = (float*)d_out;
    dim3 grid(32768 / ROWS_PER_BLOCK);  // 2048 blocks
    dim3 block(256);
    hipLaunchKernelGGL(butterfly_kernel, grid, block, 0, stream, x, tw, bias, outp);
}